// Round 19
// baseline (70.382 us; speedup 1.0000x reference)
//
#include <hip/hip_runtime.h>
#include <hip/hip_fp16.h>
#include <math.h>

#define NN   256
#define LL   256
#define HH   512
#define MLPHv 2048
#define INCv 8
#define NCOLS 150

typedef _Float16 f16x8 __attribute__((ext_vector_type(8)));
typedef __fp16   fp16x2 __attribute__((ext_vector_type(2)));
typedef float    f32x4 __attribute__((ext_vector_type(4)));
typedef unsigned short ushort_t;

union u4f16 { uint4 u; f16x8 v; };
union u1f16 { fp16x2 h; unsigned u; };

// ---------------------------------------------------------------------------
// fp32 -> fp16 hi/lo split:  a ≈ hi + lo/4096.
// ---------------------------------------------------------------------------
__device__ __forceinline__ void split1(float f, ushort_t& h, ushort_t& l)
{
    __half hh = __float2half_rn(f);
    h = __half_as_ushort(hh);
    l = __half_as_ushort(__float2half_rn((f - __half2float(hh)) * 4096.f));
}

// Packed RTZ version: RTZ hi residual <= 2^-10|a|, scaled lo captures it ->
// total err <= 2^-20|a| (failure threshold empirically 2^-15; safe).
__device__ __forceinline__ void pack8(const float* fv, uint4& hv, uint4& lv)
{
    unsigned hw[4], lw[4];
#pragma unroll
    for (int p = 0; p < 4; ++p) {
        const float a = fv[2 * p], b = fv[2 * p + 1];
        u1f16 hc, lc;
        hc.h = __builtin_amdgcn_cvt_pkrtz(a, b);
        const float r0 = (a - (float)hc.h[0]) * 4096.f;
        const float r1 = (b - (float)hc.h[1]) * 4096.f;
        lc.h = __builtin_amdgcn_cvt_pkrtz(r0, r1);
        hw[p] = hc.u;
        lw[p] = lc.u;
    }
    hv.x = hw[0]; hv.y = hw[1]; hv.z = hw[2]; hv.w = hw[3];
    lv.x = lw[0]; lv.y = lw[1]; lv.z = lw[2]; lv.w = lw[3];
}

// async global->LDS 16B per lane (linear dest: wave-uniform base + lane*16).
typedef __attribute__((address_space(3))) unsigned int lds_u32;
typedef __attribute__((address_space(1))) const unsigned int glb_u32;
__device__ __forceinline__ void gl_lds16(const ushort_t* g, ushort_t* l)
{
    __builtin_amdgcn_global_load_lds((glb_u32*)g, (lds_u32*)l, 16, 0, 0);
}
__device__ __forceinline__ void gl_lds16f(const float* g, float* l)
{
    __builtin_amdgcn_global_load_lds((glb_u32*)g, (lds_u32*)l, 16, 0, 0);
}

// Fragment-linear packing (R10-18 proven): X[row][k] lives at
// ((g*KS32 + ks)*64 + lane)*8 + j,  g=row>>4, ks=k>>5,
// lane=(row&15)+16*((k>>3)&3), j=k&7.

// ---------------------------------------------------------------------------
// 256-thread MFMA GEMM (4 waves, 2wr x 2wc, wave tile 32x32), BM=64, BN=64,
// BK=64/step, 2 blocks/CU (~65KB LDS).  Squared wave tile cuts LDS read
// duplication: A 4x->2x, total reads 96->64 KB/step.
// W = raw fp32 rows (DMA into padded LDS), converted register-direct (pkrtz).
// AMODE 0: A = packed fp16 pairs (DMA, b128 frag reads).
// AMODE 1: A = raw fp32 row-major [M][K] (z); k-contiguous staging.
// Step: STAGE(t+1) [8 DMA/thread] -> vmcnt(8) -> barrier -> {convert W (+A),
// MFMA} -> barrier.  acc = ah*bh + (ah*bl + al*bh)/4096.
// OUT=0: fp32 partial at part + bz*524288.
// OUT=1: bias+relu+split PACKED to oH/oL (next layer's A, KS32_next=64).
// ---------------------------------------------------------------------------
template <int OUT, int AMODE>
__global__ __launch_bounds__(256, 2) void gemm_v4(
    const ushort_t* __restrict__ Ah, const ushort_t* __restrict__ Al,
    const float* __restrict__ Af,
    const float* __restrict__ W, const float* __restrict__ bias,
    float* __restrict__ part, ushort_t* __restrict__ oH, ushort_t* __restrict__ oL,
    int KS32, int kchunk32, int steps, int K)
{
    __shared__ __align__(16) char sA_raw[2][16640]; // AMODE0: hi 8KB + lo 8KB; AMODE1: fp32 16x260
    __shared__ float sWf[2][4160];                  // raw fp32 W: 16 issues x 260 (pad 4)

    const int tid  = threadIdx.x;
    const int lane = tid & 63, w = tid >> 6;        // 4 waves
    const int wr   = w >> 1, wc = w & 1;            // 2 x 2 wave grid
    const int bx   = blockIdx.x, by = blockIdx.y, bz = blockIdx.z;
    const int bn   = bx * 64;
    const int kb0  = bz * kchunk32;

    f32x4 accH[2][2], accC[2][2];
#pragma unroll
    for (int r = 0; r < 2; ++r)
#pragma unroll
        for (int c = 0; c < 2; ++c) {
            accH[r][c] = (f32x4){0.f, 0.f, 0.f, 0.f};
            accC[r][c] = (f32x4){0.f, 0.f, 0.f, 0.f};
        }

    auto STAGE = [&](int ts, int b) {
        const int kb = kb0 + ts * 2;
        if (AMODE == 0) {
            // A packed: wave w stages runs w and w+4 (g = run>>1, ks = run&1)
#pragma unroll
            for (int ii = 0; ii < 2; ++ii) {
                const int run = w + ii * 4;
                const int g = run >> 1, ks = run & 1;
                const size_t fA = ((size_t)(by * 4 + g) * KS32 + kb + ks) * 512 + lane * 8;
                gl_lds16(Ah + fA, (ushort_t*)sA_raw[b] + run * 512);
                gl_lds16(Al + fA, (ushort_t*)(sA_raw[b] + 8192) + run * 512);
            }
        } else {
            // A raw fp32: wave w stages issues w*4..w*4+3 (4 rows x 64 k each)
            const int k0 = kb * 32;
#pragma unroll
            for (int ii = 0; ii < 4; ++ii) {
                const int i = w * 4 + ii;
                const float* src = Af + (size_t)(by * 64 + i * 4 + (lane >> 4)) * K + k0 + (lane & 15) * 4;
                gl_lds16f(src, (float*)sA_raw[b] + i * 260 + lane * 4);
            }
        }
        // W fp32: wave w stages issues w*4..w*4+3 (each 4 k-rows x 64 cols)
        const int k0 = kb * 32;
#pragma unroll
        for (int ii = 0; ii < 4; ++ii) {
            const int i = w * 4 + ii;
            const float* src = W + (size_t)(k0 + i * 4 + (lane >> 4)) * 2048 + bn + (lane & 15) * 4;
            gl_lds16f(src, &sWf[b][i * 260]);
        }
    };

    STAGE(0, 0);
    for (int t = 0; t < steps; ++t) {
        const int cur = t & 1;
        if (t + 1 < steps) {
            STAGE(t + 1, cur ^ 1);
            asm volatile("s_waitcnt vmcnt(8)" ::: "memory");  // step t landed; t+1 in flight
        } else {
            asm volatile("s_waitcnt vmcnt(0)" ::: "memory");
        }
        __builtin_amdgcn_s_barrier();
        asm volatile("" ::: "memory");

        // ---- register-direct W convert: this wave's TWO col-frags x 2ks ----
        f16x8 bH[2][2], bL[2][2];   // [c][ks]
#pragma unroll
        for (int c = 0; c < 2; ++c)
#pragma unroll
            for (int ks = 0; ks < 2; ++ks) {
                const int col  = wc * 32 + c * 16 + (lane & 15);
                const int koct = lane >> 4;
                float fv[8];
#pragma unroll
                for (int j = 0; j < 8; ++j) {
                    const int i = ks * 8 + koct * 2 + (j >> 2);
                    fv[j] = sWf[cur][i * 260 + (j & 3) * 64 + col];
                }
                u4f16 hv, lv;
                pack8(fv, hv.u, lv.u);
                bH[c][ks] = hv.v;
                bL[c][ks] = lv.v;
            }

        // ---- A frags (packed read or fp32 convert) + MFMA ----
        __builtin_amdgcn_s_setprio(1);
#pragma unroll
        for (int ks = 0; ks < 2; ++ks) {
            f16x8 aH[2], aL[2];
#pragma unroll
            for (int r = 0; r < 2; ++r) {
                if (AMODE == 0) {
                    const int off = (((wr * 2 + r) * 2 + ks) * 64 + lane) * 8;
                    aH[r] = *(const f16x8*)((const ushort_t*)sA_raw[cur] + off);
                    aL[r] = *(const f16x8*)((const ushort_t*)(sA_raw[cur] + 8192) + off);
                } else {
                    const int row_l = wr * 32 + r * 16 + (lane & 15);
                    const int base  = (row_l >> 2) * 260 + (row_l & 3) * 64
                                    + ks * 32 + (lane >> 4) * 8;
                    const float* p = (const float*)sA_raw[cur] + base;
                    float fv[8];
                    float4 v0 = *(const float4*)p;
                    float4 v1 = *(const float4*)(p + 4);
                    fv[0]=v0.x; fv[1]=v0.y; fv[2]=v0.z; fv[3]=v0.w;
                    fv[4]=v1.x; fv[5]=v1.y; fv[6]=v1.z; fv[7]=v1.w;
                    u4f16 hv, lv;
                    pack8(fv, hv.u, lv.u);
                    aH[r] = hv.v;
                    aL[r] = lv.v;
                }
            }
#pragma unroll
            for (int r = 0; r < 2; ++r)
#pragma unroll
                for (int c = 0; c < 2; ++c) {
                    accH[r][c] = __builtin_amdgcn_mfma_f32_16x16x32_f16(aH[r], bH[c][ks], accH[r][c], 0, 0, 0);
                    accC[r][c] = __builtin_amdgcn_mfma_f32_16x16x32_f16(aH[r], bL[c][ks], accC[r][c], 0, 0, 0);
                    accC[r][c] = __builtin_amdgcn_mfma_f32_16x16x32_f16(aL[r], bH[c][ks], accC[r][c], 0, 0, 0);
                }
        }
        __builtin_amdgcn_s_setprio(0);
        __builtin_amdgcn_s_barrier();
        asm volatile("" ::: "memory");
    }

    const float inv = 1.f / 4096.f;
#pragma unroll
    for (int r = 0; r < 2; ++r)
#pragma unroll
        for (int c = 0; c < 2; ++c) {
            const int row0 = by * 64 + wr * 32 + r * 16 + ((lane >> 4) << 2);
            const int col  = bn + wc * 32 + c * 16 + (lane & 15);
            if (OUT == 0) {
                float* po = part + (size_t)bz * 524288;
#pragma unroll
                for (int e = 0; e < 4; ++e)
                    po[(size_t)(row0 + e) * 2048 + col] = accH[r][c][e] + accC[r][c][e] * inv;
            } else {
                const float vb = bias[col];
                const int gm = by * 4 + wr * 2 + r;
                const int ks = col >> 5, koct3 = (col >> 3) & 3, j = col & 7;
                const size_t fb = ((size_t)(gm * 64 + ks) * 64) * 8 + (koct3 << 4) * 8 + j;
#pragma unroll
                for (int e = 0; e < 4; ++e) {
                    const float v = fmaxf(accH[r][c][e] + accC[r][c][e] * inv + vb, 0.f);
                    ushort_t h, l;
                    split1(v, h, l);
                    const int l16 = ((lane >> 4) << 2) + e;
                    oH[fb + (size_t)l16 * 8] = h;
                    oL[fb + (size_t)l16 * 8] = l;
                }
            }
        }
}

// ---------------------------------------------------------------------------
// reduce_pk + head-weight fusion (R18-proven):
// blocks 0..511: reduce 4 partials + bias + relu -> packed fp16 pairs.
// blocks 512..661: fused head-weight column k = b-512 (h-parallel shuffle).
// ---------------------------------------------------------------------------
__global__ __launch_bounds__(256) void reduce_fuse(
    const float* __restrict__ part, const float* __restrict__ bias,
    ushort_t* __restrict__ oH, ushort_t* __restrict__ oL,
    const float* __restrict__ cvw, const float* __restrict__ cvb,
    const float* __restrict__ cw0, const float* __restrict__ cb0,
    const float* __restrict__ cw1, const float* __restrict__ cb1,
    const float* __restrict__ cw2, const float* __restrict__ cb2,
    const float* __restrict__ nw,  const float* __restrict__ nbv,
    float* __restrict__ Mf, float* __restrict__ beta)
{
    const int b   = blockIdx.x;
    const int tid = threadIdx.x;
    if (b < 512) {
        const int ct = b & 15, rg = b >> 4;
        const int e  = tid * 4;
        const int row = rg * 8 + (e >> 7);
        const int col = ct * 128 + (e & 127);
        const size_t idx = (size_t)row * 2048 + col;
        float4 s = *(const float4*)&bias[col];
#pragma unroll
        for (int k = 0; k < 4; ++k) {
            const float4 p = *(const float4*)&part[(size_t)k * 524288 + idx];
            s.x += p.x; s.y += p.y; s.z += p.z; s.w += p.w;
        }
        s.x = fmaxf(s.x, 0.f); s.y = fmaxf(s.y, 0.f);
        s.z = fmaxf(s.z, 0.f); s.w = fmaxf(s.w, 0.f);
        ushort_t h[4], l[4];
        split1(s.x, h[0], l[0]); split1(s.y, h[1], l[1]);
        split1(s.z, h[2], l[2]); split1(s.w, h[3], l[3]);
        const int gm = row >> 4, l16 = row & 15;
        const int ks = col >> 5, koct3 = (col >> 3) & 3, j = col & 7;
        const size_t off = ((size_t)(gm * 64 + ks) * 64 + l16 + (koct3 << 4)) * 8 + j;
        ushort4 hv = {h[0], h[1], h[2], h[3]};
        ushort4 lv = {l[0], l[1], l[2], l[3]};
        *(ushort4*)&oH[off] = hv;
        *(ushort4*)&oL[off] = lv;
    } else {
        const int k = b - 512;
        const float* W; const float* B; int off, card;
        if (k < 4)        { W = cw0; B = cb0; off = 0;   card = 4;   }
        else if (k < 20)  { W = cw1; B = cb1; off = 4;   card = 16;  }
        else if (k < 148) { W = cw2; B = cb2; off = 20;  card = 128; }
        else              { W = nw;  B = nbv; off = 148; card = 2;   }
        const int kc = k - off;
        float pv[INCv + 1];
#pragma unroll
        for (int c = 0; c <= INCv; ++c) pv[c] = 0.f;
#pragma unroll
        for (int it = 0; it < 2; ++it) {
            const int h = tid + it * 256;
            const float wv = W[h * card + kc];
#pragma unroll
            for (int c = 0; c < INCv; ++c) pv[c] += cvw[h * INCv + c] * wv;
            pv[INCv] += cvb[h] * wv;
        }
        __shared__ float red[INCv + 1][4];
        const int lane = tid & 63, wave = tid >> 6;
#pragma unroll
        for (int c = 0; c <= INCv; ++c) {
            float v = pv[c];
#pragma unroll
            for (int o = 32; o >= 1; o >>= 1) v += __shfl_down(v, o, 64);
            if (lane == 0) red[c][wave] = v;
        }
        __syncthreads();
        if (tid <= INCv) {
            const float s = red[tid][0] + red[tid][1] + red[tid][2] + red[tid][3];
            if (tid < INCv) Mf[tid * NCOLS + k] = s;
            else            beta[k] = s + B[kc];
        }
    }
}

// ---------------------------------------------------------------------------
// Heads: INLINE layer-2 reduction, consumes precomputed Mf/beta (R18 form).
// ---------------------------------------------------------------------------
__global__ __launch_bounds__(256) void heads_kernel(
    const float* __restrict__ part, const float* __restrict__ b2,
    const float* __restrict__ Mf, const float* __restrict__ beta,
    const int* __restrict__ cat_target, const float* __restrict__ num_target,
    float* __restrict__ out)
{
    const int bx  = blockIdx.x;
    const int tid = threadIdx.x;
    __shared__ float Ms[INCv][128];
    __shared__ float Bsh[128];
    if (bx < 96) {
        const int g = bx >> 5;
        const int card = (g == 0) ? 4 : (g == 1) ? 16 : 128;
        const int off  = (g == 0) ? 0 : (g == 1) ? 4  : 20;
        for (int i = tid; i < card * INCv; i += 256) {
            int c = i / card, k = i % card;
            Ms[c][k] = Mf[c * NCOLS + off + k];
        }
        for (int i = tid; i < card; i += 256) Bsh[i] = beta[off + i];
        __syncthreads();

        const int idx = (bx & 31) * 256 + tid;
        const int n = idx >> 5, j = idx & 31;
        const int ci = g * 32 + j;
        const int l  = ci * 2;
        float rv[INCv];
#pragma unroll
        for (int c = 0; c < INCv; ++c) {
            const size_t e = (size_t)n * MLPHv + c * LL + l;
            float s = b2[c * LL + l];
#pragma unroll
            for (int k = 0; k < 4; ++k) s += part[(size_t)k * 524288 + e];
            rv[c] = fmaxf(s, 0.f);
        }

        float mx = -1e30f; int arg = 0;
        for (int k = 0; k < card; ++k) {
            float s = Bsh[k];
#pragma unroll
            for (int c = 0; c < INCv; ++c) s += rv[c] * Ms[c][k];
            if (s > mx) { mx = s; arg = k; }
        }
        const int tg = cat_target[n * 96 + ci];
        float sum = 0.f, stg = 0.f;
        for (int k = 0; k < card; ++k) {
            float s = Bsh[k];
#pragma unroll
            for (int c = 0; c < INCv; ++c) s += rv[c] * Ms[c][k];
            sum += expf(s - mx);
            if (k == tg) stg = s;
        }
        const float lse = mx + logf(sum);
        out[NN * LL * 3 + n * 96 + ci] = lse - stg;
        float* u = out + (size_t)(n * LL + l) * 3;
        u[0] = (float)arg; u[1] = 0.f; u[2] = 0.f;
    } else {
        const int idx = (bx - 96) * 256 + tid;  // 0..40959
        const int n = idx / 160, ni = idx % 160;
        const int l = (ni < 96) ? (2 * ni + 1) : (96 + ni);
        float rv[INCv];
#pragma unroll
        for (int c = 0; c < INCv; ++c) {
            const size_t e = (size_t)n * MLPHv + c * LL + l;
            float s = b2[c * LL + l];
#pragma unroll
            for (int k = 0; k < 4; ++k) s += part[(size_t)k * 524288 + e];
            rv[c] = fmaxf(s, 0.f);
        }
        float p0 = beta[148], p1 = beta[149];
#pragma unroll
        for (int c = 0; c < INCv; ++c) {
            p0 += rv[c] * Mf[c * NCOLS + 148];
            p1 += rv[c] * Mf[c * NCOLS + 149];
        }
        const float mu = 1.f / (1.f + expf(-p0));
        const float sp = (p1 > 20.f) ? p1 : log1pf(expf(p1));
        const float s  = sp + 1e-4f;
        const float hb = 1.f / 198.f;
        const float t  = num_target[n * 160 + ni];
        const float cp = 1.f / (1.f + expf(-((t + hb - mu) / s)));
        const float cm = 1.f / (1.f + expf(-((t - hb - mu) / s)));
        const float prob = (t < hb) ? cp : ((t > 1.f - hb) ? (1.f - cm) : (cp - cm));
        out[NN * LL * 3 + NN * 96 + n * 160 + ni] = -logf(fmaxf(prob, 1e-7f));
        float* u = out + (size_t)(n * LL + l) * 3;
        u[0] = 0.f; u[1] = rintf(mu * 99.f) / 99.f; u[2] = 0.f;
    }
}

// ---------------------------------------------------------------------------
extern "C" void kernel_launch(void* const* d_in, const int* in_sizes, int n_in,
                              void* d_out, int out_size, void* d_ws, size_t ws_size,
                              hipStream_t stream)
{
    const float* z   = (const float*)d_in[0];
    const float* w0  = (const float*)d_in[1];
    const float* b0  = (const float*)d_in[2];
    const float* w1  = (const float*)d_in[3];
    const float* b1  = (const float*)d_in[4];
    const float* w2  = (const float*)d_in[5];
    const float* b2  = (const float*)d_in[6];
    const float* cvw = (const float*)d_in[7];
    const float* cvb = (const float*)d_in[8];
    const float* cw0 = (const float*)d_in[9];
    const float* cb0 = (const float*)d_in[10];
    const float* cw1 = (const float*)d_in[11];
    const float* cb1 = (const float*)d_in[12];
    const float* cw2 = (const float*)d_in[13];
    const float* cb2 = (const float*)d_in[14];
    const float* nw  = (const float*)d_in[15];
    const float* nb  = (const float*)d_in[16];
    const float* num_target = (const float*)d_in[17];
    const int*   cat_target = (const int*)d_in[18];
    float* out = (float*)d_out;
    float* ws  = (float*)d_ws;

    size_t o = 0;
    float*    part = ws + o;                o += 4ull * 524288;   // 8 MB
    float*    Mf   = ws + o;                o += 1536;
    float*    beta = ws + o;                o += 256;
    ushort_t* r0h  = (ushort_t*)(ws + o);   o += 262144;          // packed 256x2048
    ushort_t* r0l  = (ushort_t*)(ws + o);   o += 262144;
    ushort_t* r1h  = (ushort_t*)(ws + o);   o += 262144;
    ushort_t* r1l  = (ushort_t*)(ws + o);   o += 262144;

    // 1. layer 0 (K=256, raw-fp32 A = z): r0 = pack(relu(z@w0+b0))
    gemm_v4<1, 1><<<dim3(32, 4, 1), 256, 0, stream>>>(
        nullptr, nullptr, z, w0, b0, nullptr, r0h, r0l, 8, 8, 4, 256);

    // 2-3. layer 1 (K=2048, splitK=4, packed A) + reduce/fuse -> r1 + Mf/beta
    gemm_v4<0, 0><<<dim3(32, 4, 4), 256, 0, stream>>>(
        r0h, r0l, nullptr, w1, nullptr, part, nullptr, nullptr, 64, 16, 8, 2048);
    reduce_fuse<<<dim3(662), 256, 0, stream>>>(
        part, b1, r1h, r1l, cvw, cvb, cw0, cb0, cw1, cb1, cw2, cb2, nw, nb, Mf, beta);

    // 4. layer 2 (K=2048, splitK=4) -> partials (reduced inline by heads)
    gemm_v4<0, 0><<<dim3(32, 4, 4), 256, 0, stream>>>(
        r1h, r1l, nullptr, w2, nullptr, part, nullptr, nullptr, 64, 16, 8, 2048);

    // 5. heads (inline 4-partial reduce + bias + relu)
    heads_kernel<<<dim3(256), 256, 0, stream>>>(
        part, b2, Mf, beta, cat_target, num_target, out);
}

// Round 20
// 67.342 us; speedup vs baseline: 1.0452x; 1.0452x over previous
//
#include <hip/hip_runtime.h>
#include <hip/hip_fp16.h>
#include <math.h>

#define NN   256
#define LL   256
#define HH   512
#define MLPHv 2048
#define INCv 8
#define NCOLS 150

typedef _Float16 f16x8 __attribute__((ext_vector_type(8)));
typedef float    f32x4 __attribute__((ext_vector_type(4)));
typedef unsigned short ushort_t;

union u4f16 { uint4 u; f16x8 v; };

// ---------------------------------------------------------------------------
// fp32 -> fp16 hi/lo split:  a ≈ hi + lo/4096, |residual| <= 2^-22 |a|.
// ---------------------------------------------------------------------------
__device__ __forceinline__ void split1(float f, ushort_t& h, ushort_t& l)
{
    __half hh = __float2half_rn(f);
    h = __half_as_ushort(hh);
    l = __half_as_ushort(__float2half_rn((f - __half2float(hh)) * 4096.f));
}

__device__ __forceinline__ void pack8(const float* fv, uint4& hv, uint4& lv)
{
    ushort_t h[8], l[8];
#pragma unroll
    for (int j = 0; j < 8; ++j) split1(fv[j], h[j], l[j]);
    hv.x = (unsigned)h[0] | ((unsigned)h[1] << 16);
    hv.y = (unsigned)h[2] | ((unsigned)h[3] << 16);
    hv.z = (unsigned)h[4] | ((unsigned)h[5] << 16);
    hv.w = (unsigned)h[6] | ((unsigned)h[7] << 16);
    lv.x = (unsigned)l[0] | ((unsigned)l[1] << 16);
    lv.y = (unsigned)l[2] | ((unsigned)l[3] << 16);
    lv.z = (unsigned)l[4] | ((unsigned)l[5] << 16);
    lv.w = (unsigned)l[6] | ((unsigned)l[7] << 16);
}

// async global->LDS 16B per lane (linear dest: wave-uniform base + lane*16).
typedef __attribute__((address_space(3))) unsigned int lds_u32;
typedef __attribute__((address_space(1))) const unsigned int glb_u32;
__device__ __forceinline__ void gl_lds16(const ushort_t* g, ushort_t* l)
{
    __builtin_amdgcn_global_load_lds((glb_u32*)g, (lds_u32*)l, 16, 0, 0);
}
__device__ __forceinline__ void gl_lds16f(const float* g, float* l)
{
    __builtin_amdgcn_global_load_lds((glb_u32*)g, (lds_u32*)l, 16, 0, 0);
}

// Fragment-linear packing (R10-18 proven): X[row][k] lives at
// ((g*KS32 + ks)*64 + lane)*8 + j,  g=row>>4, ks=k>>5,
// lane=(row&15)+16*((k>>3)&3), j=k&7.

// ---------------------------------------------------------------------------
// prep_small: bid<16 -> z split+pack; else -> fused head weights (150 cols).
// ---------------------------------------------------------------------------
__global__ __launch_bounds__(256) void prep_small(
    const float* __restrict__ z,
    const float* __restrict__ cvw, const float* __restrict__ cvb,
    const float* __restrict__ cw0, const float* __restrict__ cb0,
    const float* __restrict__ cw1, const float* __restrict__ cb1,
    const float* __restrict__ cw2, const float* __restrict__ cb2,
    const float* __restrict__ nw,  const float* __restrict__ nbv,
    ushort_t* __restrict__ zh, ushort_t* __restrict__ zl,
    float* __restrict__ Mf, float* __restrict__ beta)
{
    const int bid = blockIdx.x;
    const int tid = threadIdx.x;
    if (bid < 16) {
        const int idx = bid * 256 + tid;            // 0..4095
        const int r = idx >> 4, kq = idx & 15;
        const float* p = z + (size_t)r * 256 + kq * 16;
        float fv[16];
#pragma unroll
        for (int q = 0; q < 4; ++q) {
            float4 v = *(const float4*)(p + q * 4);
            fv[q * 4 + 0] = v.x; fv[q * 4 + 1] = v.y;
            fv[q * 4 + 2] = v.z; fv[q * 4 + 3] = v.w;
        }
        const int gm = r >> 4, l16 = r & 15;
#pragma unroll
        for (int o = 0; o < 2; ++o) {
            uint4 hv, lv;
            pack8(&fv[o * 8], hv, lv);
            const int koct = kq * 2 + o;
            const int ks = koct >> 2, koct3 = koct & 3;
            const size_t off = ((size_t)(gm * 8 + ks) * 64 + l16 + (koct3 << 4)) * 8;
            *(uint4*)&zh[off] = hv;
            *(uint4*)&zl[off] = lv;
        }
    } else {
        const int k = bid - 16;
        const float* W; const float* B; int off, card;
        if (k < 4)        { W = cw0; B = cb0; off = 0;   card = 4;   }
        else if (k < 20)  { W = cw1; B = cb1; off = 4;   card = 16;  }
        else if (k < 148) { W = cw2; B = cb2; off = 20;  card = 128; }
        else              { W = nw;  B = nbv; off = 148; card = 2;   }
        const int kc = k - off;
        float part[INCv + 1];
#pragma unroll
        for (int c = 0; c <= INCv; ++c) part[c] = 0.f;
#pragma unroll
        for (int it = 0; it < 2; ++it) {
            const int h = tid + it * 256;
            const float wv = W[h * card + kc];
#pragma unroll
            for (int c = 0; c < INCv; ++c) part[c] += cvw[h * INCv + c] * wv;
            part[INCv] += cvb[h] * wv;
        }
        __shared__ float red[INCv + 1][4];
        const int lane = tid & 63, wave = tid >> 6;
#pragma unroll
        for (int c = 0; c <= INCv; ++c) {
            float v = part[c];
#pragma unroll
            for (int o = 32; o >= 1; o >>= 1) v += __shfl_down(v, o, 64);
            if (lane == 0) red[c][wave] = v;
        }
        __syncthreads();
        if (tid <= INCv) {
            const float s = red[tid][0] + red[tid][1] + red[tid][2] + red[tid][3];
            if (tid < INCv) Mf[tid * NCOLS + k] = s;
            else            beta[k] = s + B[kc];
        }
    }
}

// ---------------------------------------------------------------------------
// 512-thread MFMA GEMM, BM=64, BN=64, BK=64/step, 2 blocks/CU (LDS ~65KB).
// A = packed fp16 pairs (DMA).  W = raw fp32 rows (DMA into padded LDS),
// converted REGISTER-DIRECT per wave (each wave converts exactly the W
// fragment it consumes; 2x benign duplication; bank-2-way-free reads) --
// no sWh/sWl LDS, no third barrier.
// Step: STAGE(t+1) [4 DMA/wave] -> vmcnt(4) -> barrier -> {reg-convert W,
// ds_read A, MFMA} -> barrier.  Waves 2wr x 4wc, wave tile 32x16.
// acc = ah*bh + (ah*bl + al*bh)/4096.
// OUT=0: fp32 partial at part + bz*524288.
// OUT=1: bias+relu+split PACKED to oH/oL (next layer's A, KS32_next=64).
// ---------------------------------------------------------------------------
template <int OUT>
__global__ __launch_bounds__(512, 2) void gemm_v3(
    const ushort_t* __restrict__ Ah, const ushort_t* __restrict__ Al,
    const float* __restrict__ W, const float* __restrict__ bias,
    float* __restrict__ part, ushort_t* __restrict__ oH, ushort_t* __restrict__ oL,
    int KS32, int kchunk32, int steps)
{
    __shared__ ushort_t sAh[2][4096];   // packed A hi: 8 runs x 512
    __shared__ ushort_t sAl[2][4096];   // packed A lo
    __shared__ float    sWf[2][4160];   // raw fp32 W: 16 issues x 260 (pad 4)

    const int tid  = threadIdx.x;
    const int lane = tid & 63, w = tid >> 6;        // 8 waves
    const int wr   = w >> 2, wc = w & 3;            // 2 x 4 wave grid
    const int bx   = blockIdx.x, by = blockIdx.y, bz = blockIdx.z;
    const int bn   = bx * 64;
    const int kb0  = bz * kchunk32;

    f32x4 accH[2], accC[2];
#pragma unroll
    for (int r = 0; r < 2; ++r) {
        accH[r] = (f32x4){0.f, 0.f, 0.f, 0.f};
        accC[r] = (f32x4){0.f, 0.f, 0.f, 0.f};
    }

    auto STAGE = [&](int ts, int b) {
        const int kb = kb0 + ts * 2;
        // A: wave w stages run w (g = w>>1, ks = w&1), both planes
        const int g = w >> 1, ks = w & 1;
        const size_t fA = ((size_t)(by * 4 + g) * KS32 + kb + ks) * 512 + lane * 8;
        gl_lds16(Ah + fA, &sAh[b][w * 512]);
        gl_lds16(Al + fA, &sAl[b][w * 512]);
        // W fp32: wave w stages issues w*2, w*2+1 (each 4 k-rows x 64 cols)
        const int k0 = kb * 32;
#pragma unroll
        for (int ii = 0; ii < 2; ++ii) {
            const int i = w * 2 + ii;
            const float* src = W + (size_t)(k0 + i * 4 + (lane >> 4)) * 2048 + bn + (lane & 15) * 4;
            gl_lds16f(src, &sWf[b][i * 260]);
        }
    };

    STAGE(0, 0);
    for (int t = 0; t < steps; ++t) {
        const int cur = t & 1;
        if (t + 1 < steps) {
            STAGE(t + 1, cur ^ 1);
            asm volatile("s_waitcnt vmcnt(4)" ::: "memory");  // step t landed; t+1 in flight
        } else {
            asm volatile("s_waitcnt vmcnt(0)" ::: "memory");
        }
        __builtin_amdgcn_s_barrier();
        asm volatile("" ::: "memory");

        // ---- register-direct W convert for this wave's n-frag (col16, koct) ----
        f16x8 bH[2], bL[2];
#pragma unroll
        for (int ks = 0; ks < 2; ++ks) {
            const int col  = wc * 16 + (lane & 15);
            const int koct = lane >> 4;              // k-octet within ks-half
            float fv[8];
#pragma unroll
            for (int j = 0; j < 8; ++j) {
                const int i = ks * 8 + koct * 2 + (j >> 2);
                fv[j] = sWf[cur][i * 260 + (j & 3) * 64 + col];
            }
            u4f16 hv, lv;
            pack8(fv, hv.u, lv.u);
            bH[ks] = hv.v;
            bL[ks] = lv.v;
        }

        // ---- A frags + MFMA ----
#pragma unroll
        for (int ks = 0; ks < 2; ++ks) {
            f16x8 aH[2], aL[2];
#pragma unroll
            for (int r = 0; r < 2; ++r) {
                const int off = (((wr * 2 + r) * 2 + ks) * 64 + lane) * 8;
                aH[r] = *(const f16x8*)&sAh[cur][off];
                aL[r] = *(const f16x8*)&sAl[cur][off];
            }
#pragma unroll
            for (int r = 0; r < 2; ++r) {
                accH[r] = __builtin_amdgcn_mfma_f32_16x16x32_f16(aH[r], bH[ks], accH[r], 0, 0, 0);
                accC[r] = __builtin_amdgcn_mfma_f32_16x16x32_f16(aH[r], bL[ks], accC[r], 0, 0, 0);
                accC[r] = __builtin_amdgcn_mfma_f32_16x16x32_f16(aL[r], bH[ks], accC[r], 0, 0, 0);
            }
        }
        __builtin_amdgcn_s_barrier();   // reads of buf[cur] done before re-stage
        asm volatile("" ::: "memory");
    }

    const float inv = 1.f / 4096.f;
#pragma unroll
    for (int r = 0; r < 2; ++r) {
        const int row0 = by * 64 + (wr * 2 + r) * 16 + ((lane >> 4) << 2);
        const int col  = bn + wc * 16 + (lane & 15);
        if (OUT == 0) {
            float* po = part + (size_t)bz * 524288;
#pragma unroll
            for (int e = 0; e < 4; ++e)
                po[(size_t)(row0 + e) * 2048 + col] = accH[r][e] + accC[r][e] * inv;
        } else {
            const float vb = bias[col];
            const int gm = by * 4 + wr * 2 + r;
            const int ks = col >> 5, koct3 = (col >> 3) & 3, j = col & 7;
            const size_t fb = ((size_t)(gm * 64 + ks) * 64) * 8 + (koct3 << 4) * 8 + j;
#pragma unroll
            for (int e = 0; e < 4; ++e) {
                const float v = fmaxf(accH[r][e] + accC[r][e] * inv + vb, 0.f);
                ushort_t h, l;
                split1(v, h, l);
                const int l16 = ((lane >> 4) << 2) + e;
                oH[fb + (size_t)l16 * 8] = h;
                oL[fb + (size_t)l16 * 8] = l;
            }
        }
    }
}

// ---------------------------------------------------------------------------
// Reduce 4 partials + bias + relu -> packed fp16 pairs (next layer's A).
// ---------------------------------------------------------------------------
__global__ __launch_bounds__(256) void reduce_pk(
    const float* __restrict__ part, const float* __restrict__ bias,
    ushort_t* __restrict__ oH, ushort_t* __restrict__ oL)
{
    const int b  = blockIdx.x;        // 512 blocks
    const int ct = b & 15, rg = b >> 4;
    const int e  = threadIdx.x * 4;
    const int row = rg * 8 + (e >> 7);
    const int col = ct * 128 + (e & 127);
    const size_t idx = (size_t)row * 2048 + col;
    float4 s = *(const float4*)&bias[col];
#pragma unroll
    for (int k = 0; k < 4; ++k) {
        const float4 p = *(const float4*)&part[(size_t)k * 524288 + idx];
        s.x += p.x; s.y += p.y; s.z += p.z; s.w += p.w;
    }
    s.x = fmaxf(s.x, 0.f); s.y = fmaxf(s.y, 0.f);
    s.z = fmaxf(s.z, 0.f); s.w = fmaxf(s.w, 0.f);
    ushort_t h[4], l[4];
    split1(s.x, h[0], l[0]); split1(s.y, h[1], l[1]);
    split1(s.z, h[2], l[2]); split1(s.w, h[3], l[3]);
    const int gm = row >> 4, l16 = row & 15;
    const int ks = col >> 5, koct3 = (col >> 3) & 3, j = col & 7;
    const size_t off = ((size_t)(gm * 64 + ks) * 64 + l16 + (koct3 << 4)) * 8 + j;
    ushort4 hv = {h[0], h[1], h[2], h[3]};
    ushort4 lv = {l[0], l[1], l[2], l[3]};
    *(ushort4*)&oH[off] = hv;
    *(ushort4*)&oL[off] = lv;
}

// ---------------------------------------------------------------------------
// Heads with INLINE layer-2 reduction (R11-14 proven).
// ---------------------------------------------------------------------------
__global__ __launch_bounds__(256) void heads_kernel(
    const float* __restrict__ part, const float* __restrict__ b2,
    const float* __restrict__ Mf, const float* __restrict__ beta,
    const int* __restrict__ cat_target, const float* __restrict__ num_target,
    float* __restrict__ out)
{
    const int bx  = blockIdx.x;
    const int tid = threadIdx.x;
    __shared__ float Ms[INCv][128];
    __shared__ float Bsh[128];
    if (bx < 96) {
        const int g = bx >> 5;
        const int card = (g == 0) ? 4 : (g == 1) ? 16 : 128;
        const int off  = (g == 0) ? 0 : (g == 1) ? 4  : 20;
        for (int i = tid; i < card * INCv; i += 256) {
            int c = i / card, k = i % card;
            Ms[c][k] = Mf[c * NCOLS + off + k];
        }
        for (int i = tid; i < card; i += 256) Bsh[i] = beta[off + i];
        __syncthreads();

        const int idx = (bx & 31) * 256 + tid;
        const int n = idx >> 5, j = idx & 31;
        const int ci = g * 32 + j;
        const int l  = ci * 2;
        float rv[INCv];
#pragma unroll
        for (int c = 0; c < INCv; ++c) {
            const size_t e = (size_t)n * MLPHv + c * LL + l;
            float s = b2[c * LL + l];
#pragma unroll
            for (int k = 0; k < 4; ++k) s += part[(size_t)k * 524288 + e];
            rv[c] = fmaxf(s, 0.f);
        }

        float mx = -1e30f; int arg = 0;
        for (int k = 0; k < card; ++k) {
            float s = Bsh[k];
#pragma unroll
            for (int c = 0; c < INCv; ++c) s += rv[c] * Ms[c][k];
            if (s > mx) { mx = s; arg = k; }
        }
        const int tg = cat_target[n * 96 + ci];
        float sum = 0.f, stg = 0.f;
        for (int k = 0; k < card; ++k) {
            float s = Bsh[k];
#pragma unroll
            for (int c = 0; c < INCv; ++c) s += rv[c] * Ms[c][k];
            sum += expf(s - mx);
            if (k == tg) stg = s;
        }
        const float lse = mx + logf(sum);
        out[NN * LL * 3 + n * 96 + ci] = lse - stg;
        float* u = out + (size_t)(n * LL + l) * 3;
        u[0] = (float)arg; u[1] = 0.f; u[2] = 0.f;
    } else {
        const int idx = (bx - 96) * 256 + tid;  // 0..40959
        const int n = idx / 160, ni = idx % 160;
        const int l = (ni < 96) ? (2 * ni + 1) : (96 + ni);
        float rv[INCv];
#pragma unroll
        for (int c = 0; c < INCv; ++c) {
            const size_t e = (size_t)n * MLPHv + c * LL + l;
            float s = b2[c * LL + l];
#pragma unroll
            for (int k = 0; k < 4; ++k) s += part[(size_t)k * 524288 + e];
            rv[c] = fmaxf(s, 0.f);
        }
        float p0 = beta[148], p1 = beta[149];
#pragma unroll
        for (int c = 0; c < INCv; ++c) {
            p0 += rv[c] * Mf[c * NCOLS + 148];
            p1 += rv[c] * Mf[c * NCOLS + 149];
        }
        const float mu = 1.f / (1.f + expf(-p0));
        const float sp = (p1 > 20.f) ? p1 : log1pf(expf(p1));
        const float s  = sp + 1e-4f;
        const float hb = 1.f / 198.f;
        const float t  = num_target[n * 160 + ni];
        const float cp = 1.f / (1.f + expf(-((t + hb - mu) / s)));
        const float cm = 1.f / (1.f + expf(-((t - hb - mu) / s)));
        const float prob = (t < hb) ? cp : ((t > 1.f - hb) ? (1.f - cm) : (cp - cm));
        out[NN * LL * 3 + NN * 96 + n * 160 + ni] = -logf(fmaxf(prob, 1e-7f));
        float* u = out + (size_t)(n * LL + l) * 3;
        u[0] = 0.f; u[1] = rintf(mu * 99.f) / 99.f; u[2] = 0.f;
    }
}

// ---------------------------------------------------------------------------
extern "C" void kernel_launch(void* const* d_in, const int* in_sizes, int n_in,
                              void* d_out, int out_size, void* d_ws, size_t ws_size,
                              hipStream_t stream)
{
    const float* z   = (const float*)d_in[0];
    const float* w0  = (const float*)d_in[1];
    const float* b0  = (const float*)d_in[2];
    const float* w1  = (const float*)d_in[3];
    const float* b1  = (const float*)d_in[4];
    const float* w2  = (const float*)d_in[5];
    const float* b2  = (const float*)d_in[6];
    const float* cvw = (const float*)d_in[7];
    const float* cvb = (const float*)d_in[8];
    const float* cw0 = (const float*)d_in[9];
    const float* cb0 = (const float*)d_in[10];
    const float* cw1 = (const float*)d_in[11];
    const float* cb1 = (const float*)d_in[12];
    const float* cw2 = (const float*)d_in[13];
    const float* cb2 = (const float*)d_in[14];
    const float* nw  = (const float*)d_in[15];
    const float* nb  = (const float*)d_in[16];
    const float* num_target = (const float*)d_in[17];
    const int*   cat_target = (const int*)d_in[18];
    float* out = (float*)d_out;
    float* ws  = (float*)d_ws;

    size_t o = 0;
    float*    part = ws + o;                o += 4ull * 524288;   // 8 MB
    float*    Mf   = ws + o;                o += 1536;
    float*    beta = ws + o;                o += 256;
    ushort_t* zh   = (ushort_t*)(ws + o);   o += 32768;           // packed 256x256
    ushort_t* zl   = (ushort_t*)(ws + o);   o += 32768;
    ushort_t* r0h  = (ushort_t*)(ws + o);   o += 262144;          // packed 256x2048
    ushort_t* r0l  = (ushort_t*)(ws + o);   o += 262144;
    ushort_t* r1h  = (ushort_t*)(ws + o);   o += 262144;
    ushort_t* r1l  = (ushort_t*)(ws + o);   o += 262144;

    // 1. prep: z split+pack | head-weight fusion
    prep_small<<<dim3(166), 256, 0, stream>>>(
        z, cvw, cvb, cw0, cb0, cw1, cb1, cw2, cb2, nw, nb, zh, zl, Mf, beta);

    // 2. layer 0 (K=256, full-K): r0 = pack(relu(z@w0+b0))
    gemm_v3<1><<<dim3(32, 4, 1), 512, 0, stream>>>(
        zh, zl, w0, b0, nullptr, r0h, r0l, 8, 8, 4);

    // 3-4. layer 1 (K=2048, splitK=4) + reduce -> r1 packed
    gemm_v3<0><<<dim3(32, 4, 4), 512, 0, stream>>>(
        r0h, r0l, w1, nullptr, part, nullptr, nullptr, 64, 16, 8);
    reduce_pk<<<dim3(512), 256, 0, stream>>>(part, b1, r1h, r1l);

    // 5. layer 2 (K=2048, splitK=4) -> partials (reduced inline by heads)
    gemm_v3<0><<<dim3(32, 4, 4), 512, 0, stream>>>(
        r1h, r1l, w2, nullptr, part, nullptr, nullptr, 64, 16, 8);

    // 6. heads (inline 4-partial reduce + bias + relu)
    heads_kernel<<<dim3(256), 256, 0, stream>>>(
        part, b2, Mf, beta, cat_target, num_target, out);
}